// Round 3
// baseline (471.059 us; speedup 1.0000x reference)
//
#include <hip/hip_runtime.h>
#include <hip/hip_bf16.h>
#include <string.h>

#define SEQ 4096
#define DIM 512
#define NH  8
#define HD  64

typedef __attribute__((ext_vector_type(4))) float  f32x4;
typedef __attribute__((ext_vector_type(8))) short  bf16x8;
typedef __attribute__((ext_vector_type(4))) short  s16x4;

// f32 -> bf16 via hardware convert (RNE on gfx950)
__device__ __forceinline__ unsigned short f2bfh(float f){
    union { __hip_bfloat16 h; unsigned short u; } cv;
    cv.h = __float2bfloat16(f);
    return cv.u;
}

__device__ __forceinline__ bf16x8 cvt8(f32x4 lo, f32x4 hi){
    bf16x8 r;
    r[0]=(short)f2bfh(lo[0]); r[1]=(short)f2bfh(lo[1]);
    r[2]=(short)f2bfh(lo[2]); r[3]=(short)f2bfh(lo[3]);
    r[4]=(short)f2bfh(hi[0]); r[5]=(short)f2bfh(hi[1]);
    r[6]=(short)f2bfh(hi[2]); r[7]=(short)f2bfh(hi[3]);
    return r;
}

__device__ __forceinline__ bf16x8 load8f(const float* p){
    f32x4 lo = *(const f32x4*)p;
    f32x4 hi = *(const f32x4*)(p+4);
    return cvt8(lo, hi);
}

#define FENCE_LDS() do { \
    __builtin_amdgcn_sched_barrier(0); \
    asm volatile("s_waitcnt lgkmcnt(0)" ::: "memory"); \
    __builtin_amdgcn_sched_barrier(0); \
} while(0)

// ---------------------------------------------------------------------------
// Kernel 0: one-time f32 -> bf16 conversion of x and the four weight matrices.
// ---------------------------------------------------------------------------
__global__ __launch_bounds__(256) void cvt5_kernel(
    const float* __restrict__ x,  const float* __restrict__ wq,
    const float* __restrict__ wk, const float* __restrict__ wv,
    const float* __restrict__ wo,
    unsigned short* __restrict__ xb,  unsigned short* __restrict__ wqb,
    unsigned short* __restrict__ wkb, unsigned short* __restrict__ wvb,
    unsigned short* __restrict__ wob)
{
    int b = blockIdx.x;
    const float* src; unsigned short* dst; int base;
    if (b < 1024){ src = x; dst = xb; base = b; }
    else {
        int t  = (b - 1024) >> 7;
        base   = (b - 1024) & 127;
        src = (t==0) ? wq  : (t==1) ? wk  : (t==2) ? wv  : wo;
        dst = (t==0) ? wqb : (t==1) ? wkb : (t==2) ? wvb : wob;
    }
    size_t i = ((size_t)base*256 + threadIdx.x)*8;
    f32x4 lo = *(const f32x4*)(src + i);
    f32x4 hi = *(const f32x4*)(src + i + 4);
    *(bf16x8*)(dst + i) = cvt8(lo, hi);
}

// ---------------------------------------------------------------------------
// Kernel 1 (fast path): fused Q/K/V projections from pre-converted bf16.
// ---------------------------------------------------------------------------
__global__ __launch_bounds__(256) void proj_qkv_b_kernel(
    const unsigned short* __restrict__ xb,
    const unsigned short* __restrict__ Wqb, const float* __restrict__ bq,
    const unsigned short* __restrict__ Wkb, const float* __restrict__ bk,
    const unsigned short* __restrict__ Wvb, const float* __restrict__ bv,
    unsigned short* __restrict__ Qb, unsigned short* __restrict__ Kb,
    unsigned short* __restrict__ Vt)
{
    const int z = blockIdx.z;
    const unsigned short* W = (z==0) ? Wqb : ((z==1) ? Wkb : Wvb);
    const float* bb = (z==0) ? bq : ((z==1) ? bk : bv);
    const int wv  = threadIdx.x >> 6;
    const int l   = threadIdx.x & 63;
    const int g   = l >> 4;
    const int l15 = l & 15;
    const int r0  = blockIdx.x * 128 + wv * 32;
    const int c0  = blockIdx.y * 64;

    f32x4 acc[2][4];
    #pragma unroll
    for(int s=0;s<2;s++)
        #pragma unroll
        for(int d=0;d<4;d++) acc[s][d] = (f32x4){0.f,0.f,0.f,0.f};

    for(int kt=0; kt<DIM; kt+=32){
        bf16x8 a[2];
        #pragma unroll
        for(int s=0;s<2;s++)
            a[s] = *(const bf16x8*)(xb + (size_t)(r0+s*16+l15)*DIM + kt + g*8);
        #pragma unroll
        for(int d=0;d<4;d++){
            bf16x8 b = *(const bf16x8*)(W + (size_t)(c0+d*16+l15)*DIM + kt + g*8);
            #pragma unroll
            for(int s=0;s<2;s++)
                acc[s][d] = __builtin_amdgcn_mfma_f32_16x16x32_bf16(a[s], b, acc[s][d], 0,0,0);
        }
    }

    #pragma unroll
    for(int d=0;d<4;d++){
        float bias = bb[c0 + d*16 + l15];
        #pragma unroll
        for(int s=0;s<2;s++){
            if(z == 2){
                s16x4 pk;
                #pragma unroll
                for(int r=0;r<4;r++) pk[r] = (short)f2bfh(acc[s][d][r] + bias);
                *(s16x4*)(Vt + (size_t)(c0+d*16+l15)*SEQ + r0 + s*16 + g*4) = pk;
            } else {
                unsigned short* o = (z==0) ? Qb : Kb;
                #pragma unroll
                for(int r=0;r<4;r++)
                    o[(size_t)(r0+s*16+g*4+r)*DIM + c0 + d*16 + l15] = f2bfh(acc[s][d][r] + bias);
            }
        }
    }
}

// ---------------------------------------------------------------------------
// Kernel 1 (fallback): round-1 proj with in-loop f32->bf16 cvt
// ---------------------------------------------------------------------------
__global__ __launch_bounds__(256) void proj_qkv_kernel(
    const float* __restrict__ x,
    const float* __restrict__ Wq, const float* __restrict__ bq,
    const float* __restrict__ Wk, const float* __restrict__ bk,
    const float* __restrict__ Wv, const float* __restrict__ bv,
    unsigned short* __restrict__ Qb, unsigned short* __restrict__ Kb,
    unsigned short* __restrict__ Vt)
{
    const int z = blockIdx.z;
    const float* W  = (z==0) ? Wq : ((z==1) ? Wk : Wv);
    const float* bb = (z==0) ? bq : ((z==1) ? bk : bv);
    const int wv  = threadIdx.x >> 6;
    const int l   = threadIdx.x & 63;
    const int g   = l >> 4;
    const int l15 = l & 15;
    const int r0  = blockIdx.x * 128 + wv * 32;
    const int c0  = blockIdx.y * 64;

    f32x4 acc[2][4];
    #pragma unroll
    for(int s=0;s<2;s++)
        #pragma unroll
        for(int d=0;d<4;d++) acc[s][d] = (f32x4){0.f,0.f,0.f,0.f};

    for(int kt=0; kt<DIM; kt+=32){
        bf16x8 a[2];
        #pragma unroll
        for(int s=0;s<2;s++)
            a[s] = load8f(x + (size_t)(r0+s*16+l15)*DIM + kt + g*8);
        #pragma unroll
        for(int d=0;d<4;d++){
            bf16x8 b = load8f(W + (size_t)(c0+d*16+l15)*DIM + kt + g*8);
            #pragma unroll
            for(int s=0;s<2;s++)
                acc[s][d] = __builtin_amdgcn_mfma_f32_16x16x32_bf16(a[s], b, acc[s][d], 0,0,0);
        }
    }

    #pragma unroll
    for(int d=0;d<4;d++){
        float bias = bb[c0 + d*16 + l15];
        #pragma unroll
        for(int s=0;s<2;s++){
            if(z == 2){
                s16x4 pk;
                #pragma unroll
                for(int r=0;r<4;r++) pk[r] = (short)f2bfh(acc[s][d][r] + bias);
                *(s16x4*)(Vt + (size_t)(c0+d*16+l15)*SEQ + r0 + s*16 + g*4) = pk;
            } else {
                unsigned short* o = (z==0) ? Qb : Kb;
                #pragma unroll
                for(int r=0;r<4;r++)
                    o[(size_t)(r0+s*16+g*4+r)*DIM + c0 + d*16 + l15] = f2bfh(acc[s][d][r] + bias);
            }
        }
    }
}

// ---------------------------------------------------------------------------
// Kernel 2: two-pass attention, 8 waves/block (2 row-halves x 4 K-chunks).
// Block = 32 q-rows of one head, 512 threads. Wave (rh,kc): 16 rows, 1024 keys.
// Grid 1024 blocks x 8 waves = 32 waves/CU (4 blocks/CU exactly).
// P tile double-buffered in LDS -> single wave-local lgkmcnt fence per tile.
// Exact cross-wave max merge (pass A) and fixed-order f32 num/den merge
// (aliased over P region) keep the math bit-identical to the 4-wave version.
// ---------------------------------------------------------------------------
#define PSTRIDE 68

__global__ __launch_bounds__(512, 8) void attn_kernel(
    const unsigned short* __restrict__ Qb,
    const unsigned short* __restrict__ Kb,
    const unsigned short* __restrict__ Vt,
    unsigned short* __restrict__ Ab,
    float k1f)   // GIST_A * scaling
{
    // [8 waves][2 bufs][16][PSTRIDE] ushort = 34816 B, aliased after the loop
    // with merge buf [2][3][64][21] f32 = 32252 B; + mmax [8][16] f32 = 512 B.
    __shared__ __align__(16) unsigned char smem[34816 + 512];
    float* mmax = (float*)(smem + 34816);

    const int wv  = threadIdx.x >> 6;
    const int l   = threadIdx.x & 63;
    const int g   = l >> 4;
    const int l15 = l & 15;
    const int h   = blockIdx.y;
    const int rh  = wv >> 2;            // row half (16 rows)
    const int kc  = wv & 3;             // key chunk (1024 keys)
    const int R0  = blockIdx.x * 32 + rh * 16;
    const int kb  = kc * (SEQ/4);

    unsigned short* pbuf0 = (unsigned short*)(smem + wv*4352);
    unsigned short* pbuf1 = (unsigned short*)(smem + wv*4352 + 2176);

    // Q fragments: 16 rows x 64 dims
    bf16x8 aq[2];
    #pragma unroll
    for(int kh=0;kh<2;kh++)
        aq[kh] = *(const bf16x8*)(Qb + (size_t)(R0+l15)*DIM + h*HD + kh*32 + g*8);

    // ---- pass A: per-wave partial raw row max ----
    float mx[4];
    mx[0]=mx[1]=mx[2]=mx[3]=-3.0e38f;

    for(int k0=kb; k0<kb+SEQ/4; k0+=64){
        #pragma unroll
        for(int ks=0;ks<4;ks++){
            const unsigned short* kp = Kb + (size_t)(k0+ks*16+l15)*DIM + h*HD + g*8;
            bf16x8 b0 = *(const bf16x8*)kp;
            bf16x8 b1 = *(const bf16x8*)(kp + 32);
            f32x4 acc = (f32x4){0.f,0.f,0.f,0.f};
            acc = __builtin_amdgcn_mfma_f32_16x16x32_bf16(aq[0], b0, acc, 0,0,0);
            acc = __builtin_amdgcn_mfma_f32_16x16x32_bf16(aq[1], b1, acc, 0,0,0);
            #pragma unroll
            for(int r=0;r<4;r++) mx[r] = fmaxf(mx[r], acc[r]);
        }
    }
    #pragma unroll
    for(int off=1; off<16; off<<=1)
        #pragma unroll
        for(int r=0;r<4;r++)
            mx[r] = fmaxf(mx[r], __shfl_xor(mx[r], off, 64));

    if(l15 == 0){
        #pragma unroll
        for(int r=0;r<4;r++)
            mmax[wv*16 + g*4 + r] = mx[r];
    }
    __syncthreads();
    // per-row fused-exp constant c = GIST_B - k1f*m  (t = k1f*s + c)
    float crow[4];
    #pragma unroll
    for(int r=0;r<4;r++){
        float m01 = fmaxf(mmax[(rh*4+0)*16 + g*4 + r], mmax[(rh*4+1)*16 + g*4 + r]);
        float m23 = fmaxf(mmax[(rh*4+2)*16 + g*4 + r], mmax[(rh*4+3)*16 + g*4 + r]);
        crow[r] = 1064986823.0f - k1f * fmaxf(m01, m23);
    }

    // ---- pass B ----
    f32x4 oacc[4];
    #pragma unroll
    for(int d=0;d<4;d++) oacc[d] = (f32x4){0.f,0.f,0.f,0.f};
    f32x4 dacc = (f32x4){0.f,0.f,0.f,0.f};

    bf16x8 ones;
    #pragma unroll
    for(int j=0;j<8;j++) ones[j] = (short)0x3F80;   // bf16 1.0

    int t = 0;
    for(int k0=kb; k0<kb+SEQ/4; k0+=64, t^=1){
        unsigned short* pl = t ? pbuf1 : pbuf0;
        #pragma unroll
        for(int ks=0;ks<4;ks++){
            const unsigned short* kp = Kb + (size_t)(k0+ks*16+l15)*DIM + h*HD + g*8;
            bf16x8 b0 = *(const bf16x8*)kp;
            bf16x8 b1 = *(const bf16x8*)(kp + 32);
            f32x4 acc = (f32x4){0.f,0.f,0.f,0.f};
            acc = __builtin_amdgcn_mfma_f32_16x16x32_bf16(aq[0], b0, acc, 0,0,0);
            acc = __builtin_amdgcn_mfma_f32_16x16x32_bf16(aq[1], b1, acc, 0,0,0);
            #pragma unroll
            for(int r=0;r<4;r++){
                // fexp: t = k1f*s + (B - k1f*m); underflow clamp dropped
                // (scores bounded: |s| < 2, so t >= ~1.0e9 >> 2^23 always)
                float tt = fmaf(k1f, acc[r], crow[r]);
                float p  = __int_as_float((int)tt);
                pl[(g*4+r)*PSTRIDE + ks*16 + l15] = f2bfh(p);
            }
        }
        FENCE_LDS();   // wave-local: P writes visible to cross-lane reads

        #pragma unroll
        for(int ks2=0; ks2<2; ks2++){
            bf16x8 pa = *(const bf16x8*)&pl[l15*PSTRIDE + ks2*32 + g*8];
            dacc = __builtin_amdgcn_mfma_f32_16x16x32_bf16(pa, ones, dacc, 0,0,0);
            #pragma unroll
            for(int d=0;d<4;d++){
                bf16x8 bv_ = *(const bf16x8*)(Vt + (size_t)(h*HD + d*16 + l15)*SEQ + k0 + ks2*32 + g*8);
                oacc[d] = __builtin_amdgcn_mfma_f32_16x16x32_bf16(pa, bv_, oacc[d], 0,0,0);
            }
        }
        // no trailing fence: next tile writes the other P buffer (no WAR),
        // and the next tile's lgkmcnt(0) drains these reads before reuse.
    }

    // ---- cross-wave merge of num/den (fixed order, f32) ----
    __syncthreads();          // everyone done with the P region
    float* merge = (float*)smem;   // [2][3][64][21]
    if(kc != 0){
        float* mb = merge + (((size_t)rh*3 + (kc-1))*64 + l)*21;
        #pragma unroll
        for(int d=0;d<4;d++)
            #pragma unroll
            for(int r=0;r<4;r++)
                mb[d*4+r] = oacc[d][r];
        #pragma unroll
        for(int r=0;r<4;r++) mb[16+r] = dacc[r];
    }
    __syncthreads();
    if(kc == 0){
        #pragma unroll
        for(int w=0;w<3;w++){
            const float* mb = merge + (((size_t)rh*3 + w)*64 + l)*21;
            #pragma unroll
            for(int d=0;d<4;d++)
                #pragma unroll
                for(int r=0;r<4;r++)
                    oacc[d][r] += mb[d*4+r];
            #pragma unroll
            for(int r=0;r<4;r++) dacc[r] += mb[16+r];
        }
        float inv[4];
        #pragma unroll
        for(int r=0;r<4;r++) inv[r] = 1.0f / dacc[r];
        #pragma unroll
        for(int d=0;d<4;d++)
            #pragma unroll
            for(int r=0;r<4;r++)
                Ab[(size_t)(R0+g*4+r)*DIM + h*HD + d*16 + l15] =
                    f2bfh(oacc[d][r] * inv[r]);
    }
}

// ---------------------------------------------------------------------------
// Kernel 3 (fast path): output projection from bf16 Wout. f32 output.
// ---------------------------------------------------------------------------
__global__ __launch_bounds__(256) void proj_out_b_kernel(
    const unsigned short* __restrict__ Ab,
    const unsigned short* __restrict__ Wob,
    float* __restrict__ out)
{
    const int wv  = threadIdx.x >> 6;
    const int l   = threadIdx.x & 63;
    const int g   = l >> 4;
    const int l15 = l & 15;
    const int r0  = blockIdx.x * 128 + wv * 32;
    const int c0  = blockIdx.y * 64;

    f32x4 acc[2][4];
    #pragma unroll
    for(int s=0;s<2;s++)
        #pragma unroll
        for(int d=0;d<4;d++) acc[s][d] = (f32x4){0.f,0.f,0.f,0.f};

    for(int kt=0; kt<DIM; kt+=32){
        bf16x8 a[2];
        #pragma unroll
        for(int s=0;s<2;s++)
            a[s] = *(const bf16x8*)(Ab + (size_t)(r0+s*16+l15)*DIM + kt + g*8);
        #pragma unroll
        for(int d=0;d<4;d++){
            bf16x8 b = *(const bf16x8*)(Wob + (size_t)(c0+d*16+l15)*DIM + kt + g*8);
            #pragma unroll
            for(int s=0;s<2;s++)
                acc[s][d] = __builtin_amdgcn_mfma_f32_16x16x32_bf16(a[s], b, acc[s][d], 0,0,0);
        }
    }

    #pragma unroll
    for(int s=0;s<2;s++)
        #pragma unroll
        for(int d=0;d<4;d++)
            #pragma unroll
            for(int r=0;r<4;r++)
                out[(size_t)(r0+s*16+g*4+r)*DIM + c0 + d*16 + l15] = acc[s][d][r];
}

// fallback out-proj (f32 Wout with in-loop cvt)
__global__ __launch_bounds__(256) void proj_out_kernel(
    const unsigned short* __restrict__ Ab,
    const float* __restrict__ Wout,
    float* __restrict__ out)
{
    const int wv  = threadIdx.x >> 6;
    const int l   = threadIdx.x & 63;
    const int g   = l >> 4;
    const int l15 = l & 15;
    const int r0  = blockIdx.x * 128 + wv * 32;
    const int c0  = blockIdx.y * 64;

    f32x4 acc[2][4];
    #pragma unroll
    for(int s=0;s<2;s++)
        #pragma unroll
        for(int d=0;d<4;d++) acc[s][d] = (f32x4){0.f,0.f,0.f,0.f};

    for(int kt=0; kt<DIM; kt+=32){
        bf16x8 a[2];
        #pragma unroll
        for(int s=0;s<2;s++)
            a[s] = *(const bf16x8*)(Ab + (size_t)(r0+s*16+l15)*DIM + kt + g*8);
        #pragma unroll
        for(int d=0;d<4;d++){
            bf16x8 b = load8f(Wout + (size_t)(c0+d*16+l15)*DIM + kt + g*8);
            #pragma unroll
            for(int s=0;s<2;s++)
                acc[s][d] = __builtin_amdgcn_mfma_f32_16x16x32_bf16(a[s], b, acc[s][d], 0,0,0);
        }
    }

    #pragma unroll
    for(int s=0;s<2;s++)
        #pragma unroll
        for(int d=0;d<4;d++)
            #pragma unroll
            for(int r=0;r<4;r++)
                out[(size_t)(r0+s*16+g*4+r)*DIM + c0 + d*16 + l15] = acc[s][d][r];
}

// ---------------------------------------------------------------------------
extern "C" void kernel_launch(void* const* d_in, const int* in_sizes, int n_in,
                              void* d_out, int out_size, void* d_ws, size_t ws_size,
                              hipStream_t stream)
{
    const float* x    = (const float*)d_in[0];
    const float* Wq   = (const float*)d_in[1];
    const float* bq   = (const float*)d_in[2];
    const float* Wk   = (const float*)d_in[3];
    const float* bk   = (const float*)d_in[4];
    const float* Wv   = (const float*)d_in[5];
    const float* bv   = (const float*)d_in[6];
    const float* Wout = (const float*)d_in[7];
    float* out = (float*)d_out;

    unsigned short* Qb = (unsigned short*)d_ws;          // [SEQ][DIM] bf16
    unsigned short* Kb = Qb + (size_t)SEQ*DIM;           // [SEQ][DIM] bf16
    unsigned short* Vt = Kb + (size_t)SEQ*DIM;           // [DIM][SEQ] bf16 (transposed)
    unsigned short* Ab = Vt + (size_t)SEQ*DIM;           // [SEQ][DIM] bf16
    unsigned short* xb = Ab + (size_t)SEQ*DIM;           // [SEQ][DIM] bf16
    unsigned short* Wqb = xb  + (size_t)SEQ*DIM;         // [DIM][DIM] bf16
    unsigned short* Wkb = Wqb + (size_t)DIM*DIM;
    unsigned short* Wvb = Wkb + (size_t)DIM*DIM;
    unsigned short* Wob = Wvb + (size_t)DIM*DIM;
    const size_t needed = ((size_t)SEQ*DIM*5 + (size_t)DIM*DIM*4) * 2;

    // quake fast inverse sqrt of HEAD_DIM (replicates numpy f32 ops)
    float xx = 64.0f;
    float x2 = xx * 0.5f;
    int ii; memcpy(&ii, &xx, 4);
    ii = 1597463007 - (ii >> 1);
    float y; memcpy(&y, &ii, 4);
    y = y * (1.5f - x2 * y * y);
    const float scaling = y;
    const float k1f = 12102203.17133801f * scaling;   // GIST_A * scaling (f32)

    if(ws_size >= needed){
        cvt5_kernel<<<dim3(1536), 256, 0, stream>>>(
            x, Wq, Wk, Wv, Wout, xb, Wqb, Wkb, Wvb, Wob);
        proj_qkv_b_kernel<<<dim3(SEQ/128, DIM/64, 3), 256, 0, stream>>>(
            xb, Wqb, bq, Wkb, bk, Wvb, bv, Qb, Kb, Vt);
        attn_kernel<<<dim3(SEQ/32, NH), 512, 0, stream>>>(Qb, Kb, Vt, Ab, k1f);
        proj_out_b_kernel<<<dim3(SEQ/128, DIM/64), 256, 0, stream>>>(Ab, Wob, out);
    } else {
        proj_qkv_kernel<<<dim3(SEQ/128, DIM/64, 3), 256, 0, stream>>>(
            x, Wq, bq, Wk, bk, Wv, bv, Qb, Kb, Vt);
        attn_kernel<<<dim3(SEQ/32, NH), 512, 0, stream>>>(Qb, Kb, Vt, Ab, k1f);
        proj_out_kernel<<<dim3(SEQ/128, DIM/64), 256, 0, stream>>>(Ab, Wout, out);
    }
}

// Round 4
// 299.512 us; speedup vs baseline: 1.5728x; 1.5728x over previous
//
#include <hip/hip_runtime.h>
#include <hip/hip_bf16.h>
#include <string.h>

#define SEQ 4096
#define DIM 512
#define NH  8
#define HD  64

typedef __attribute__((ext_vector_type(4))) float  f32x4;
typedef __attribute__((ext_vector_type(8))) short  bf16x8;
typedef __attribute__((ext_vector_type(4))) short  s16x4;

// f32 -> bf16 via hardware convert (RNE on gfx950)
__device__ __forceinline__ unsigned short f2bfh(float f){
    union { __hip_bfloat16 h; unsigned short u; } cv;
    cv.h = __float2bfloat16(f);
    return cv.u;
}

__device__ __forceinline__ bf16x8 cvt8(f32x4 lo, f32x4 hi){
    bf16x8 r;
    r[0]=(short)f2bfh(lo[0]); r[1]=(short)f2bfh(lo[1]);
    r[2]=(short)f2bfh(lo[2]); r[3]=(short)f2bfh(lo[3]);
    r[4]=(short)f2bfh(hi[0]); r[5]=(short)f2bfh(hi[1]);
    r[6]=(short)f2bfh(hi[2]); r[7]=(short)f2bfh(hi[3]);
    return r;
}

__device__ __forceinline__ bf16x8 load8f(const float* p){
    f32x4 lo = *(const f32x4*)p;
    f32x4 hi = *(const f32x4*)(p+4);
    return cvt8(lo, hi);
}

// LDS-only fence: orders LDS ops (memory clobber) but is NOT a scheduling
// wall for VALU/MFMA, and already-issued global loads keep flying (vmcnt
// untouched). Rule-18 hazard doesn't apply: consumers after the fence are
// compiler-visible ds_reads (memory ops), which the clobber does order.
#define FENCE_LDS() asm volatile("s_waitcnt lgkmcnt(0)" ::: "memory")

// ---------------------------------------------------------------------------
// Kernel 0: one-time f32 -> bf16 conversion of x and the four weight matrices.
// ---------------------------------------------------------------------------
__global__ __launch_bounds__(256) void cvt5_kernel(
    const float* __restrict__ x,  const float* __restrict__ wq,
    const float* __restrict__ wk, const float* __restrict__ wv,
    const float* __restrict__ wo,
    unsigned short* __restrict__ xb,  unsigned short* __restrict__ wqb,
    unsigned short* __restrict__ wkb, unsigned short* __restrict__ wvb,
    unsigned short* __restrict__ wob)
{
    int b = blockIdx.x;
    const float* src; unsigned short* dst; int base;
    if (b < 1024){ src = x; dst = xb; base = b; }
    else {
        int t  = (b - 1024) >> 7;
        base   = (b - 1024) & 127;
        src = (t==0) ? wq  : (t==1) ? wk  : (t==2) ? wv  : wo;
        dst = (t==0) ? wqb : (t==1) ? wkb : (t==2) ? wvb : wob;
    }
    size_t i = ((size_t)base*256 + threadIdx.x)*8;
    f32x4 lo = *(const f32x4*)(src + i);
    f32x4 hi = *(const f32x4*)(src + i + 4);
    *(bf16x8*)(dst + i) = cvt8(lo, hi);
}

// ---------------------------------------------------------------------------
// Kernel 1 (fast path): fused Q/K/V projections from pre-converted bf16.
// ---------------------------------------------------------------------------
__global__ __launch_bounds__(256) void proj_qkv_b_kernel(
    const unsigned short* __restrict__ xb,
    const unsigned short* __restrict__ Wqb, const float* __restrict__ bq,
    const unsigned short* __restrict__ Wkb, const float* __restrict__ bk,
    const unsigned short* __restrict__ Wvb, const float* __restrict__ bv,
    unsigned short* __restrict__ Qb, unsigned short* __restrict__ Kb,
    unsigned short* __restrict__ Vt)
{
    const int z = blockIdx.z;
    const unsigned short* W = (z==0) ? Wqb : ((z==1) ? Wkb : Wvb);
    const float* bb = (z==0) ? bq : ((z==1) ? bk : bv);
    const int wv  = threadIdx.x >> 6;
    const int l   = threadIdx.x & 63;
    const int g   = l >> 4;
    const int l15 = l & 15;
    const int r0  = blockIdx.x * 128 + wv * 32;
    const int c0  = blockIdx.y * 64;

    f32x4 acc[2][4];
    #pragma unroll
    for(int s=0;s<2;s++)
        #pragma unroll
        for(int d=0;d<4;d++) acc[s][d] = (f32x4){0.f,0.f,0.f,0.f};

    for(int kt=0; kt<DIM; kt+=32){
        bf16x8 a[2];
        #pragma unroll
        for(int s=0;s<2;s++)
            a[s] = *(const bf16x8*)(xb + (size_t)(r0+s*16+l15)*DIM + kt + g*8);
        #pragma unroll
        for(int d=0;d<4;d++){
            bf16x8 b = *(const bf16x8*)(W + (size_t)(c0+d*16+l15)*DIM + kt + g*8);
            #pragma unroll
            for(int s=0;s<2;s++)
                acc[s][d] = __builtin_amdgcn_mfma_f32_16x16x32_bf16(a[s], b, acc[s][d], 0,0,0);
        }
    }

    #pragma unroll
    for(int d=0;d<4;d++){
        float bias = bb[c0 + d*16 + l15];
        #pragma unroll
        for(int s=0;s<2;s++){
            if(z == 2){
                s16x4 pk;
                #pragma unroll
                for(int r=0;r<4;r++) pk[r] = (short)f2bfh(acc[s][d][r] + bias);
                *(s16x4*)(Vt + (size_t)(c0+d*16+l15)*SEQ + r0 + s*16 + g*4) = pk;
            } else {
                unsigned short* o = (z==0) ? Qb : Kb;
                #pragma unroll
                for(int r=0;r<4;r++)
                    o[(size_t)(r0+s*16+g*4+r)*DIM + c0 + d*16 + l15] = f2bfh(acc[s][d][r] + bias);
            }
        }
    }
}

// ---------------------------------------------------------------------------
// Kernel 1 (fallback): proj with in-loop f32->bf16 cvt
// ---------------------------------------------------------------------------
__global__ __launch_bounds__(256) void proj_qkv_kernel(
    const float* __restrict__ x,
    const float* __restrict__ Wq, const float* __restrict__ bq,
    const float* __restrict__ Wk, const float* __restrict__ bk,
    const float* __restrict__ Wv, const float* __restrict__ bv,
    unsigned short* __restrict__ Qb, unsigned short* __restrict__ Kb,
    unsigned short* __restrict__ Vt)
{
    const int z = blockIdx.z;
    const float* W  = (z==0) ? Wq : ((z==1) ? Wk : Wv);
    const float* bb = (z==0) ? bq : ((z==1) ? bk : bv);
    const int wv  = threadIdx.x >> 6;
    const int l   = threadIdx.x & 63;
    const int g   = l >> 4;
    const int l15 = l & 15;
    const int r0  = blockIdx.x * 128 + wv * 32;
    const int c0  = blockIdx.y * 64;

    f32x4 acc[2][4];
    #pragma unroll
    for(int s=0;s<2;s++)
        #pragma unroll
        for(int d=0;d<4;d++) acc[s][d] = (f32x4){0.f,0.f,0.f,0.f};

    for(int kt=0; kt<DIM; kt+=32){
        bf16x8 a[2];
        #pragma unroll
        for(int s=0;s<2;s++)
            a[s] = load8f(x + (size_t)(r0+s*16+l15)*DIM + kt + g*8);
        #pragma unroll
        for(int d=0;d<4;d++){
            bf16x8 b = load8f(W + (size_t)(c0+d*16+l15)*DIM + kt + g*8);
            #pragma unroll
            for(int s=0;s<2;s++)
                acc[s][d] = __builtin_amdgcn_mfma_f32_16x16x32_bf16(a[s], b, acc[s][d], 0,0,0);
        }
    }

    #pragma unroll
    for(int d=0;d<4;d++){
        float bias = bb[c0 + d*16 + l15];
        #pragma unroll
        for(int s=0;s<2;s++){
            if(z == 2){
                s16x4 pk;
                #pragma unroll
                for(int r=0;r<4;r++) pk[r] = (short)f2bfh(acc[s][d][r] + bias);
                *(s16x4*)(Vt + (size_t)(c0+d*16+l15)*SEQ + r0 + s*16 + g*4) = pk;
            } else {
                unsigned short* o = (z==0) ? Qb : Kb;
                #pragma unroll
                for(int r=0;r<4;r++)
                    o[(size_t)(r0+s*16+g*4+r)*DIM + c0 + d*16 + l15] = f2bfh(acc[s][d][r] + bias);
            }
        }
    }
}

// ---------------------------------------------------------------------------
// Kernel 2: two-pass attention. R2 shape (4 waves x [32 q-rows, 1024 keys],
// 1024 blocks, launch_bounds(256,4) -> VGPR cap 128, no spill) with:
//  - double-buffered P (one lgkm fence per tile, no WAR fence)
//  - fences without sched_barrier walls (compiler can overlap phases)
//  - pass A: persistent-slot K prefetch (reload slot right after consumption)
//  - pass B: unroll-2 tile loop; V loads issued before P ds_reads/den MFMAs
// ---------------------------------------------------------------------------
#define PSTRIDE 68

__global__ __launch_bounds__(256, 4) void attn_kernel(
    const unsigned short* __restrict__ Qb,
    const unsigned short* __restrict__ Kb,
    const unsigned short* __restrict__ Vt,
    unsigned short* __restrict__ Ab,
    float k1f)   // GIST_A * scaling
{
    // per wave: 2 P buffers of 32x68 ushort (4352 B) -> 8704 B; 4 waves.
    // After the loop the region is reused for the cross-wave merge buffer.
    __shared__ __align__(16) unsigned char smem[4*8704 + 512];
    float* mmax = (float*)(smem + 4*8704);   // [4][32]

    const int wv  = threadIdx.x >> 6;
    const int l   = threadIdx.x & 63;
    const int g   = l >> 4;
    const int l15 = l & 15;
    const int h   = blockIdx.y;
    const int r0  = blockIdx.x * 32;
    const int kb  = wv * (SEQ/4);
    const int kend= kb + SEQ/4;

    unsigned short* pb0 = (unsigned short*)(smem + wv*8704);
    unsigned short* pb1 = pb0 + 2176;

    // Q fragments: 32 rows x 64 dims
    bf16x8 aq[2][2];
    #pragma unroll
    for(int s=0;s<2;s++)
        #pragma unroll
        for(int kh=0;kh<2;kh++)
            aq[s][kh] = *(const bf16x8*)(Qb + (size_t)(r0+s*16+l15)*DIM + h*HD + kh*32 + g*8);

    // ---- pass A: per-wave raw row max, persistent-slot K prefetch ----
    float mx[2][4];
    #pragma unroll
    for(int s=0;s<2;s++){ mx[s][0]=mx[s][1]=mx[s][2]=mx[s][3]=-3.0e38f; }

    bf16x8 kf[4][2];
    #pragma unroll
    for(int ks=0;ks<4;ks++){
        const unsigned short* kp = Kb + (size_t)(kb+ks*16+l15)*DIM + h*HD + g*8;
        kf[ks][0] = *(const bf16x8*)kp;
        kf[ks][1] = *(const bf16x8*)(kp + 32);
    }
    for(int k0=kb; k0<kend; k0+=64){
        int kn = (k0+64 < kend) ? (k0+64) : kb;   // wrap: leaves kf = K[kb] for pass B
        #pragma unroll
        for(int ks=0;ks<4;ks++){
            f32x4 a0 = (f32x4){0.f,0.f,0.f,0.f};
            f32x4 a1 = (f32x4){0.f,0.f,0.f,0.f};
            a0 = __builtin_amdgcn_mfma_f32_16x16x32_bf16(aq[0][0], kf[ks][0], a0, 0,0,0);
            a0 = __builtin_amdgcn_mfma_f32_16x16x32_bf16(aq[0][1], kf[ks][1], a0, 0,0,0);
            a1 = __builtin_amdgcn_mfma_f32_16x16x32_bf16(aq[1][0], kf[ks][0], a1, 0,0,0);
            a1 = __builtin_amdgcn_mfma_f32_16x16x32_bf16(aq[1][1], kf[ks][1], a1, 0,0,0);
            // slot consumed -> reload with next tile (latency covered by rest of tile)
            const unsigned short* kp = Kb + (size_t)(kn+ks*16+l15)*DIM + h*HD + g*8;
            kf[ks][0] = *(const bf16x8*)kp;
            kf[ks][1] = *(const bf16x8*)(kp + 32);
            #pragma unroll
            for(int r=0;r<4;r++){
                mx[0][r] = fmaxf(mx[0][r], a0[r]);
                mx[1][r] = fmaxf(mx[1][r], a1[r]);
            }
        }
    }
    #pragma unroll
    for(int off=1; off<16; off<<=1)
        #pragma unroll
        for(int s=0;s<2;s++)
            #pragma unroll
            for(int r=0;r<4;r++)
                mx[s][r] = fmaxf(mx[s][r], __shfl_xor(mx[s][r], off, 64));

    if(l15 == 0){
        #pragma unroll
        for(int s=0;s<2;s++)
            #pragma unroll
            for(int r=0;r<4;r++)
                mmax[wv*32 + s*16 + g*4 + r] = mx[s][r];
    }
    __syncthreads();
    // per-row fused-exp constant c = GIST_B - k1f*m_raw  (t = k1f*s + c)
    float crow[2][4];
    #pragma unroll
    for(int s=0;s<2;s++)
        #pragma unroll
        for(int r=0;r<4;r++){
            float m = fmaxf(fmaxf(mmax[ 0 + s*16 + g*4 + r], mmax[32 + s*16 + g*4 + r]),
                            fmaxf(mmax[64 + s*16 + g*4 + r], mmax[96 + s*16 + g*4 + r]));
            crow[s][r] = 1064986823.0f - k1f*m;
        }

    // ---- pass B ----
    f32x4 oacc[2][4];
    #pragma unroll
    for(int s=0;s<2;s++)
        #pragma unroll
        for(int d=0;d<4;d++) oacc[s][d] = (f32x4){0.f,0.f,0.f,0.f};
    f32x4 dacc[2];
    dacc[0] = (f32x4){0.f,0.f,0.f,0.f};
    dacc[1] = (f32x4){0.f,0.f,0.f,0.f};

    bf16x8 ones;
    #pragma unroll
    for(int j=0;j<8;j++) ones[j] = (short)0x3F80;   // bf16 1.0

    int t = 0;
    #pragma unroll 2
    for(int k0=kb; k0<kend; k0+=64, t^=1){
        unsigned short* pl = t ? pb1 : pb0;
        // QK^T + fexp + P-write (kf holds this tile on entry for k0==kb;
        // otherwise loaded per-slot here, hoistable into prev PV via unroll-2)
        #pragma unroll
        for(int ks=0;ks<4;ks++){
            bf16x8 b0, b1;
            if(k0 == kb){ b0 = kf[ks][0]; b1 = kf[ks][1]; }
            else {
                const unsigned short* kp = Kb + (size_t)(k0+ks*16+l15)*DIM + h*HD + g*8;
                b0 = *(const bf16x8*)kp;
                b1 = *(const bf16x8*)(kp + 32);
            }
            f32x4 a0 = (f32x4){0.f,0.f,0.f,0.f};
            f32x4 a1 = (f32x4){0.f,0.f,0.f,0.f};
            a0 = __builtin_amdgcn_mfma_f32_16x16x32_bf16(aq[0][0], b0, a0, 0,0,0);
            a0 = __builtin_amdgcn_mfma_f32_16x16x32_bf16(aq[0][1], b1, a0, 0,0,0);
            a1 = __builtin_amdgcn_mfma_f32_16x16x32_bf16(aq[1][0], b0, a1, 0,0,0);
            a1 = __builtin_amdgcn_mfma_f32_16x16x32_bf16(aq[1][1], b1, a1, 0,0,0);
            #pragma unroll
            for(int r=0;r<4;r++){
                float t0 = fmaf(k1f, a0[r], crow[0][r]);
                float t1 = fmaf(k1f, a1[r], crow[1][r]);
                pl[(   g*4+r)*PSTRIDE + ks*16 + l15] = f2bfh(__int_as_float((int)t0));
                pl[(16+g*4+r)*PSTRIDE + ks*16 + l15] = f2bfh(__int_as_float((int)t1));
            }
        }
        FENCE_LDS();   // wave-local: all P ds_writes drained before cross-lane reads

        // PV: issue V(ks2=0) loads, then P reads + den MFMAs (latency cover),
        // then V(ks2=1) loads, then the V MFMAs.
        bf16x8 v0[4], v1[4];
        #pragma unroll
        for(int d=0;d<4;d++)
            v0[d] = *(const bf16x8*)(Vt + (size_t)(h*HD + d*16 + l15)*SEQ + k0 + g*8);
        bf16x8 pa[2][2];
        #pragma unroll
        for(int ks2=0;ks2<2;ks2++)
            #pragma unroll
            for(int s=0;s<2;s++)
                pa[ks2][s] = *(const bf16x8*)&pl[(s*16+l15)*PSTRIDE + ks2*32 + g*8];
        #pragma unroll
        for(int ks2=0;ks2<2;ks2++)
            #pragma unroll
            for(int s=0;s<2;s++)
                dacc[s] = __builtin_amdgcn_mfma_f32_16x16x32_bf16(pa[ks2][s], ones, dacc[s], 0,0,0);
        #pragma unroll
        for(int d=0;d<4;d++)
            v1[d] = *(const bf16x8*)(Vt + (size_t)(h*HD + d*16 + l15)*SEQ + k0 + 32 + g*8);
        #pragma unroll
        for(int d=0;d<4;d++)
            #pragma unroll
            for(int s=0;s<2;s++)
                oacc[s][d] = __builtin_amdgcn_mfma_f32_16x16x32_bf16(pa[0][s], v0[d], oacc[s][d], 0,0,0);
        #pragma unroll
        for(int d=0;d<4;d++)
            #pragma unroll
            for(int s=0;s<2;s++)
                oacc[s][d] = __builtin_amdgcn_mfma_f32_16x16x32_bf16(pa[1][s], v1[d], oacc[s][d], 0,0,0);
        // no trailing fence: next tile writes the other P buffer; its fence
        // drains these reads before this buffer is overwritten again.
    }

    // ---- cross-wave merge of num/den (fixed order, f32, bit-identical) ----
    __syncthreads();          // everyone done with the P region
    float* merge = (float*)smem;   // [3 waves][64 lanes][up to 40 f32] fits in 34816B
    if(wv != 0){
        float* mb = merge + ((size_t)(wv-1)*64 + l)*40;
        #pragma unroll
        for(int s=0;s<2;s++)
            #pragma unroll
            for(int d=0;d<4;d++)
                #pragma unroll
                for(int r=0;r<4;r++)
                    mb[(s*4+d)*4 + r] = oacc[s][d][r];
        #pragma unroll
        for(int s=0;s<2;s++)
            #pragma unroll
            for(int r=0;r<4;r++)
                mb[32 + s*4 + r] = dacc[s][r];
    }
    __syncthreads();
    if(wv == 0){
        #pragma unroll
        for(int w=0;w<3;w++){
            const float* mb = merge + ((size_t)w*64 + l)*40;
            #pragma unroll
            for(int s=0;s<2;s++)
                #pragma unroll
                for(int d=0;d<4;d++)
                    #pragma unroll
                    for(int r=0;r<4;r++)
                        oacc[s][d][r] += mb[(s*4+d)*4 + r];
            #pragma unroll
            for(int s=0;s<2;s++)
                #pragma unroll
                for(int r=0;r<4;r++)
                    dacc[s][r] += mb[32 + s*4 + r];
        }
        #pragma unroll
        for(int s=0;s<2;s++){
            float inv[4];
            #pragma unroll
            for(int r=0;r<4;r++) inv[r] = 1.0f / dacc[s][r];
            #pragma unroll
            for(int d=0;d<4;d++)
                #pragma unroll
                for(int r=0;r<4;r++)
                    Ab[(size_t)(r0+s*16+g*4+r)*DIM + h*HD + d*16 + l15] =
                        f2bfh(oacc[s][d][r] * inv[r]);
        }
    }
}

// ---------------------------------------------------------------------------
// Kernel 3 (fast path): output projection from bf16 Wout. f32 output.
// ---------------------------------------------------------------------------
__global__ __launch_bounds__(256) void proj_out_b_kernel(
    const unsigned short* __restrict__ Ab,
    const unsigned short* __restrict__ Wob,
    float* __restrict__ out)
{
    const int wv  = threadIdx.x >> 6;
    const int l   = threadIdx.x & 63;
    const int g   = l >> 4;
    const int l15 = l & 15;
    const int r0  = blockIdx.x * 128 + wv * 32;
    const int c0  = blockIdx.y * 64;

    f32x4 acc[2][4];
    #pragma unroll
    for(int s=0;s<2;s++)
        #pragma unroll
        for(int d=0;d<4;d++) acc[s][d] = (f32x4){0.f,0.f,0.f,0.f};

    for(int kt=0; kt<DIM; kt+=32){
        bf16x8 a[2];
        #pragma unroll
        for(int s=0;s<2;s++)
            a[s] = *(const bf16x8*)(Ab + (size_t)(r0+s*16+l15)*DIM + kt + g*8);
        #pragma unroll
        for(int d=0;d<4;d++){
            bf16x8 b = *(const bf16x8*)(Wob + (size_t)(c0+d*16+l15)*DIM + kt + g*8);
            #pragma unroll
            for(int s=0;s<2;s++)
                acc[s][d] = __builtin_amdgcn_mfma_f32_16x16x32_bf16(a[s], b, acc[s][d], 0,0,0);
        }
    }

    #pragma unroll
    for(int s=0;s<2;s++)
        #pragma unroll
        for(int d=0;d<4;d++)
            #pragma unroll
            for(int r=0;r<4;r++)
                out[(size_t)(r0+s*16+g*4+r)*DIM + c0 + d*16 + l15] = acc[s][d][r];
}

// fallback out-proj (f32 Wout with in-loop cvt)
__global__ __launch_bounds__(256) void proj_out_kernel(
    const unsigned short* __restrict__ Ab,
    const float* __restrict__ Wout,
    float* __restrict__ out)
{
    const int wv  = threadIdx.x >> 6;
    const int l   = threadIdx.x & 63;
    const int g   = l >> 4;
    const int l15 = l & 15;
    const int r0  = blockIdx.x * 128 + wv * 32;
    const int c0  = blockIdx.y * 64;

    f32x4 acc[2][4];
    #pragma unroll
    for(int s=0;s<2;s++)
        #pragma unroll
        for(int d=0;d<4;d++) acc[s][d] = (f32x4){0.f,0.f,0.f,0.f};

    for(int kt=0; kt<DIM; kt+=32){
        bf16x8 a[2];
        #pragma unroll
        for(int s=0;s<2;s++)
            a[s] = *(const bf16x8*)(Ab + (size_t)(r0+s*16+l15)*DIM + kt + g*8);
        #pragma unroll
        for(int d=0;d<4;d++){
            bf16x8 b = load8f(Wout + (size_t)(c0+d*16+l15)*DIM + kt + g*8);
            #pragma unroll
            for(int s=0;s<2;s++)
                acc[s][d] = __builtin_amdgcn_mfma_f32_16x16x32_bf16(a[s], b, acc[s][d], 0,0,0);
        }
    }

    #pragma unroll
    for(int s=0;s<2;s++)
        #pragma unroll
        for(int d=0;d<4;d++)
            #pragma unroll
            for(int r=0;r<4;r++)
                out[(size_t)(r0+s*16+g*4+r)*DIM + c0 + d*16 + l15] = acc[s][d][r];
}

// ---------------------------------------------------------------------------
extern "C" void kernel_launch(void* const* d_in, const int* in_sizes, int n_in,
                              void* d_out, int out_size, void* d_ws, size_t ws_size,
                              hipStream_t stream)
{
    const float* x    = (const float*)d_in[0];
    const float* Wq   = (const float*)d_in[1];
    const float* bq   = (const float*)d_in[2];
    const float* Wk   = (const float*)d_in[3];
    const float* bk   = (const float*)d_in[4];
    const float* Wv   = (const float*)d_in[5];
    const float* bv   = (const float*)d_in[6];
    const float* Wout = (const float*)d_in[7];
    float* out = (float*)d_out;

    unsigned short* Qb = (unsigned short*)d_ws;          // [SEQ][DIM] bf16
    unsigned short* Kb = Qb + (size_t)SEQ*DIM;           // [SEQ][DIM] bf16
    unsigned short* Vt = Kb + (size_t)SEQ*DIM;           // [DIM][SEQ] bf16 (transposed)
    unsigned short* Ab = Vt + (size_t)SEQ*DIM;           // [SEQ][DIM] bf16
    unsigned short* xb = Ab + (size_t)SEQ*DIM;           // [SEQ][DIM] bf16
    unsigned short* Wqb = xb  + (size_t)SEQ*DIM;         // [DIM][DIM] bf16
    unsigned short* Wkb = Wqb + (size_t)DIM*DIM;
    unsigned short* Wvb = Wkb + (size_t)DIM*DIM;
    unsigned short* Wob = Wvb + (size_t)DIM*DIM;
    const size_t needed = ((size_t)SEQ*DIM*5 + (size_t)DIM*DIM*4) * 2;

    // quake fast inverse sqrt of HEAD_DIM (replicates numpy f32 ops)
    float xx = 64.0f;
    float x2 = xx * 0.5f;
    int ii; memcpy(&ii, &xx, 4);
    ii = 1597463007 - (ii >> 1);
    float y; memcpy(&y, &ii, 4);
    y = y * (1.5f - x2 * y * y);
    const float scaling = y;
    const float k1f = 12102203.17133801f * scaling;   // GIST_A * scaling (f32)

    if(ws_size >= needed){
        cvt5_kernel<<<dim3(1536), 256, 0, stream>>>(
            x, Wq, Wk, Wv, Wout, xb, Wqb, Wkb, Wvb, Wob);
        proj_qkv_b_kernel<<<dim3(SEQ/128, DIM/64, 3), 256, 0, stream>>>(
            xb, Wqb, bq, Wkb, bk, Wvb, bv, Qb, Kb, Vt);
        attn_kernel<<<dim3(SEQ/32, NH), 256, 0, stream>>>(Qb, Kb, Vt, Ab, k1f);
        proj_out_b_kernel<<<dim3(SEQ/128, DIM/64), 256, 0, stream>>>(Ab, Wob, out);
    } else {
        proj_qkv_kernel<<<dim3(SEQ/128, DIM/64, 3), 256, 0, stream>>>(
            x, Wq, bq, Wk, bk, Wv, bv, Qb, Kb, Vt);
        attn_kernel<<<dim3(SEQ/32, NH), 256, 0, stream>>>(Qb, Kb, Vt, Ab, k1f);
        proj_out_kernel<<<dim3(SEQ/128, DIM/64), 256, 0, stream>>>(Ab, Wout, out);
    }
}

// Round 5
// 235.610 us; speedup vs baseline: 1.9993x; 1.2712x over previous
//
#include <hip/hip_runtime.h>
#include <hip/hip_bf16.h>
#include <string.h>

#define SEQ 4096
#define DIM 512
#define NH  8
#define HD  64
#define SEQP (SEQ + 128)   // padded V row stride: 8448B = 33*256B -> channel-spread

typedef __attribute__((ext_vector_type(4))) float  f32x4;
typedef __attribute__((ext_vector_type(8))) short  bf16x8;
typedef __attribute__((ext_vector_type(4))) short  s16x4;

// f32 -> bf16 via hardware convert (RNE on gfx950)
__device__ __forceinline__ unsigned short f2bfh(float f){
    union { __hip_bfloat16 h; unsigned short u; } cv;
    cv.h = __float2bfloat16(f);
    return cv.u;
}

__device__ __forceinline__ bf16x8 cvt8(f32x4 lo, f32x4 hi){
    bf16x8 r;
    r[0]=(short)f2bfh(lo[0]); r[1]=(short)f2bfh(lo[1]);
    r[2]=(short)f2bfh(lo[2]); r[3]=(short)f2bfh(lo[3]);
    r[4]=(short)f2bfh(hi[0]); r[5]=(short)f2bfh(hi[1]);
    r[6]=(short)f2bfh(hi[2]); r[7]=(short)f2bfh(hi[3]);
    return r;
}

__device__ __forceinline__ bf16x8 load8f(const float* p){
    f32x4 lo = *(const f32x4*)p;
    f32x4 hi = *(const f32x4*)(p+4);
    return cvt8(lo, hi);
}

// LDS-only fence: orders this wave's LDS ops; not a VALU/MFMA schedule wall.
#define FENCE_LDS() asm volatile("s_waitcnt lgkmcnt(0)" ::: "memory")

// ---------------------------------------------------------------------------
// Kernel 0: one-time f32 -> bf16 conversion of x and the four weight matrices.
// ---------------------------------------------------------------------------
__global__ __launch_bounds__(256) void cvt5_kernel(
    const float* __restrict__ x,  const float* __restrict__ wq,
    const float* __restrict__ wk, const float* __restrict__ wv,
    const float* __restrict__ wo,
    unsigned short* __restrict__ xb,  unsigned short* __restrict__ wqb,
    unsigned short* __restrict__ wkb, unsigned short* __restrict__ wvb,
    unsigned short* __restrict__ wob)
{
    int b = blockIdx.x;
    const float* src; unsigned short* dst; int base;
    if (b < 1024){ src = x; dst = xb; base = b; }
    else {
        int t  = (b - 1024) >> 7;
        base   = (b - 1024) & 127;
        src = (t==0) ? wq  : (t==1) ? wk  : (t==2) ? wv  : wo;
        dst = (t==0) ? wqb : (t==1) ? wkb : (t==2) ? wvb : wob;
    }
    size_t i = ((size_t)base*256 + threadIdx.x)*8;
    f32x4 lo = *(const f32x4*)(src + i);
    f32x4 hi = *(const f32x4*)(src + i + 4);
    *(bf16x8*)(dst + i) = cvt8(lo, hi);
}

// ---------------------------------------------------------------------------
// Kernel 1 (fast path): fused Q/K/V projections from pre-converted bf16.
// Q -> Qb[SEQ][DIM] (row-major, as before)
// K -> Kh[NH][SEQ][HD]   (head-contiguous rows: fragment = contiguous 2KB)
// V -> Vtp[NH][HD][SEQP] (transposed per head, padded rows: channel-spread)
// head == blockIdx.y since c0 = by*64 and HD = 64.
// ---------------------------------------------------------------------------
__global__ __launch_bounds__(256) void proj_qkv_b_kernel(
    const unsigned short* __restrict__ xb,
    const unsigned short* __restrict__ Wqb, const float* __restrict__ bq,
    const unsigned short* __restrict__ Wkb, const float* __restrict__ bk,
    const unsigned short* __restrict__ Wvb, const float* __restrict__ bv,
    unsigned short* __restrict__ Qb, unsigned short* __restrict__ Kh,
    unsigned short* __restrict__ Vtp)
{
    const int z = blockIdx.z;
    const unsigned short* W = (z==0) ? Wqb : ((z==1) ? Wkb : Wvb);
    const float* bb = (z==0) ? bq : ((z==1) ? bk : bv);
    const int wv  = threadIdx.x >> 6;
    const int l   = threadIdx.x & 63;
    const int g   = l >> 4;
    const int l15 = l & 15;
    const int r0  = blockIdx.x * 128 + wv * 32;
    const int c0  = blockIdx.y * 64;
    const int hy  = blockIdx.y;

    f32x4 acc[2][4];
    #pragma unroll
    for(int s=0;s<2;s++)
        #pragma unroll
        for(int d=0;d<4;d++) acc[s][d] = (f32x4){0.f,0.f,0.f,0.f};

    for(int kt=0; kt<DIM; kt+=32){
        bf16x8 a[2];
        #pragma unroll
        for(int s=0;s<2;s++)
            a[s] = *(const bf16x8*)(xb + (size_t)(r0+s*16+l15)*DIM + kt + g*8);
        #pragma unroll
        for(int d=0;d<4;d++){
            bf16x8 b = *(const bf16x8*)(W + (size_t)(c0+d*16+l15)*DIM + kt + g*8);
            #pragma unroll
            for(int s=0;s<2;s++)
                acc[s][d] = __builtin_amdgcn_mfma_f32_16x16x32_bf16(a[s], b, acc[s][d], 0,0,0);
        }
    }

    #pragma unroll
    for(int d=0;d<4;d++){
        float bias = bb[c0 + d*16 + l15];
        #pragma unroll
        for(int s=0;s<2;s++){
            if(z == 2){
                s16x4 pk;
                #pragma unroll
                for(int r=0;r<4;r++) pk[r] = (short)f2bfh(acc[s][d][r] + bias);
                *(s16x4*)(Vtp + ((size_t)hy*HD + d*16+l15)*SEQP + r0 + s*16 + g*4) = pk;
            } else if(z == 1){
                #pragma unroll
                for(int r=0;r<4;r++)
                    Kh[((size_t)hy*SEQ + r0+s*16+g*4+r)*HD + d*16 + l15] =
                        f2bfh(acc[s][d][r] + bias);
            } else {
                #pragma unroll
                for(int r=0;r<4;r++)
                    Qb[(size_t)(r0+s*16+g*4+r)*DIM + c0 + d*16 + l15] =
                        f2bfh(acc[s][d][r] + bias);
            }
        }
    }
}

// ---------------------------------------------------------------------------
// Kernel 1 (fallback): same outputs, f32 weights with in-loop cvt
// ---------------------------------------------------------------------------
__global__ __launch_bounds__(256) void proj_qkv_kernel(
    const float* __restrict__ x,
    const float* __restrict__ Wq, const float* __restrict__ bq,
    const float* __restrict__ Wk, const float* __restrict__ bk,
    const float* __restrict__ Wv, const float* __restrict__ bv,
    unsigned short* __restrict__ Qb, unsigned short* __restrict__ Kh,
    unsigned short* __restrict__ Vtp)
{
    const int z = blockIdx.z;
    const float* W  = (z==0) ? Wq : ((z==1) ? Wk : Wv);
    const float* bb = (z==0) ? bq : ((z==1) ? bk : bv);
    const int wv  = threadIdx.x >> 6;
    const int l   = threadIdx.x & 63;
    const int g   = l >> 4;
    const int l15 = l & 15;
    const int r0  = blockIdx.x * 128 + wv * 32;
    const int c0  = blockIdx.y * 64;
    const int hy  = blockIdx.y;

    f32x4 acc[2][4];
    #pragma unroll
    for(int s=0;s<2;s++)
        #pragma unroll
        for(int d=0;d<4;d++) acc[s][d] = (f32x4){0.f,0.f,0.f,0.f};

    for(int kt=0; kt<DIM; kt+=32){
        bf16x8 a[2];
        #pragma unroll
        for(int s=0;s<2;s++)
            a[s] = load8f(x + (size_t)(r0+s*16+l15)*DIM + kt + g*8);
        #pragma unroll
        for(int d=0;d<4;d++){
            bf16x8 b = load8f(W + (size_t)(c0+d*16+l15)*DIM + kt + g*8);
            #pragma unroll
            for(int s=0;s<2;s++)
                acc[s][d] = __builtin_amdgcn_mfma_f32_16x16x32_bf16(a[s], b, acc[s][d], 0,0,0);
        }
    }

    #pragma unroll
    for(int d=0;d<4;d++){
        float bias = bb[c0 + d*16 + l15];
        #pragma unroll
        for(int s=0;s<2;s++){
            if(z == 2){
                s16x4 pk;
                #pragma unroll
                for(int r=0;r<4;r++) pk[r] = (short)f2bfh(acc[s][d][r] + bias);
                *(s16x4*)(Vtp + ((size_t)hy*HD + d*16+l15)*SEQP + r0 + s*16 + g*4) = pk;
            } else if(z == 1){
                #pragma unroll
                for(int r=0;r<4;r++)
                    Kh[((size_t)hy*SEQ + r0+s*16+g*4+r)*HD + d*16 + l15] =
                        f2bfh(acc[s][d][r] + bias);
            } else {
                #pragma unroll
                for(int r=0;r<4;r++)
                    Qb[(size_t)(r0+s*16+g*4+r)*DIM + c0 + d*16 + l15] =
                        f2bfh(acc[s][d][r] + bias);
            }
        }
    }
}

// ---------------------------------------------------------------------------
// Kernel 2: two-pass attention. R2 structure (4 waves x [32 q-rows, 1024 keys],
// 1024 blocks, launch_bounds(256,4)) with:
//  - head-contiguous Kh (fragment loads = one 2KB contiguous block)
//  - padded Vtp (lane stride 33*256B -> 16 distinct L2 channels)
//  - double-buffered P: ONE lgkmcnt fence per tile (no WAR fence)
// ---------------------------------------------------------------------------
#define PSTRIDE 68

__global__ __launch_bounds__(256, 4) void attn_kernel(
    const unsigned short* __restrict__ Qb,
    const unsigned short* __restrict__ Kh,
    const unsigned short* __restrict__ Vtp,
    unsigned short* __restrict__ Ab,
    float k1f)   // GIST_A * scaling
{
    // per wave: 2 P buffers of 32x68 ushort (4352 B) -> 8704 B; 4 waves.
    // Region reused by the cross-wave merge buffer after the loop.
    __shared__ __align__(16) unsigned char smem[4*8704 + 512];
    float* mmax = (float*)(smem + 4*8704);   // [4][32]

    const int wv  = threadIdx.x >> 6;
    const int l   = threadIdx.x & 63;
    const int g   = l >> 4;
    const int l15 = l & 15;
    const int h   = blockIdx.y;
    const int r0  = blockIdx.x * 32;
    const int kb  = wv * (SEQ/4);
    const int kend= kb + SEQ/4;

    unsigned short* pb0 = (unsigned short*)(smem + wv*8704);
    unsigned short* pb1 = pb0 + 2176;

    const unsigned short* Khh = Kh  + (size_t)h*SEQ*HD;
    const unsigned short* Vh  = Vtp + (size_t)h*HD*SEQP;

    // Q fragments: 32 rows x 64 dims
    bf16x8 aq[2][2];
    #pragma unroll
    for(int s=0;s<2;s++)
        #pragma unroll
        for(int kh=0;kh<2;kh++)
            aq[s][kh] = *(const bf16x8*)(Qb + (size_t)(r0+s*16+l15)*DIM + h*HD + kh*32 + g*8);

    // ---- pass A: per-wave partial raw row max ----
    float mx[2][4];
    #pragma unroll
    for(int s=0;s<2;s++){ mx[s][0]=mx[s][1]=mx[s][2]=mx[s][3]=-3.0e38f; }

    for(int k0=kb; k0<kend; k0+=64){
        #pragma unroll
        for(int ks=0;ks<4;ks++){
            const unsigned short* kp = Khh + ((size_t)(k0+ks*16+l15))*HD + g*8;
            bf16x8 b0 = *(const bf16x8*)kp;
            bf16x8 b1 = *(const bf16x8*)(kp + 32);
            #pragma unroll
            for(int s=0;s<2;s++){
                f32x4 acc = (f32x4){0.f,0.f,0.f,0.f};
                acc = __builtin_amdgcn_mfma_f32_16x16x32_bf16(aq[s][0], b0, acc, 0,0,0);
                acc = __builtin_amdgcn_mfma_f32_16x16x32_bf16(aq[s][1], b1, acc, 0,0,0);
                #pragma unroll
                for(int r=0;r<4;r++) mx[s][r] = fmaxf(mx[s][r], acc[r]);
            }
        }
    }
    #pragma unroll
    for(int off=1; off<16; off<<=1)
        #pragma unroll
        for(int s=0;s<2;s++)
            #pragma unroll
            for(int r=0;r<4;r++)
                mx[s][r] = fmaxf(mx[s][r], __shfl_xor(mx[s][r], off, 64));

    if(l15 == 0){
        #pragma unroll
        for(int s=0;s<2;s++)
            #pragma unroll
            for(int r=0;r<4;r++)
                mmax[wv*32 + s*16 + g*4 + r] = mx[s][r];
    }
    __syncthreads();
    // per-row fused-exp constant c = GIST_B - k1f*m_raw  (t = k1f*s + c)
    float crow[2][4];
    #pragma unroll
    for(int s=0;s<2;s++)
        #pragma unroll
        for(int r=0;r<4;r++){
            float m = fmaxf(fmaxf(mmax[ 0 + s*16 + g*4 + r], mmax[32 + s*16 + g*4 + r]),
                            fmaxf(mmax[64 + s*16 + g*4 + r], mmax[96 + s*16 + g*4 + r]));
            crow[s][r] = 1064986823.0f - k1f*m;
        }

    // ---- pass B ----
    f32x4 oacc[2][4];
    #pragma unroll
    for(int s=0;s<2;s++)
        #pragma unroll
        for(int d=0;d<4;d++) oacc[s][d] = (f32x4){0.f,0.f,0.f,0.f};
    f32x4 dacc[2];
    dacc[0] = (f32x4){0.f,0.f,0.f,0.f};
    dacc[1] = (f32x4){0.f,0.f,0.f,0.f};

    bf16x8 ones;
    #pragma unroll
    for(int j=0;j<8;j++) ones[j] = (short)0x3F80;   // bf16 1.0

    int t = 0;
    for(int k0=kb; k0<kend; k0+=64, t^=1){
        unsigned short* pl = t ? pb1 : pb0;
        #pragma unroll
        for(int ks=0;ks<4;ks++){
            const unsigned short* kp = Khh + ((size_t)(k0+ks*16+l15))*HD + g*8;
            bf16x8 b0 = *(const bf16x8*)kp;
            bf16x8 b1 = *(const bf16x8*)(kp + 32);
            #pragma unroll
            for(int s=0;s<2;s++){
                f32x4 acc = (f32x4){0.f,0.f,0.f,0.f};
                acc = __builtin_amdgcn_mfma_f32_16x16x32_bf16(aq[s][0], b0, acc, 0,0,0);
                acc = __builtin_amdgcn_mfma_f32_16x16x32_bf16(aq[s][1], b1, acc, 0,0,0);
                #pragma unroll
                for(int r=0;r<4;r++){
                    float tt = fmaf(k1f, acc[r], crow[s][r]);
                    pl[(s*16+g*4+r)*PSTRIDE + ks*16 + l15] = f2bfh(__int_as_float((int)tt));
                }
            }
        }
        FENCE_LDS();   // wave-local: P ds_writes drained before cross-lane reads

        #pragma unroll
        for(int ks2=0; ks2<2; ks2++){
            bf16x8 pa[2];
            #pragma unroll
            for(int s=0;s<2;s++)
                pa[s] = *(const bf16x8*)&pl[(s*16+l15)*PSTRIDE + ks2*32 + g*8];
            #pragma unroll
            for(int s=0;s<2;s++)
                dacc[s] = __builtin_amdgcn_mfma_f32_16x16x32_bf16(pa[s], ones, dacc[s], 0,0,0);
            #pragma unroll
            for(int d=0;d<4;d++){
                bf16x8 bv_ = *(const bf16x8*)(Vh + ((size_t)(d*16+l15))*SEQP + k0 + ks2*32 + g*8);
                #pragma unroll
                for(int s=0;s<2;s++)
                    oacc[s][d] = __builtin_amdgcn_mfma_f32_16x16x32_bf16(pa[s], bv_, oacc[s][d], 0,0,0);
            }
        }
        // no trailing fence: next tile writes the other P buffer; its fence
        // drains these reads before this buffer is overwritten again.
    }

    // ---- cross-wave merge of num/den (fixed order, f32, bit-identical) ----
    __syncthreads();          // everyone done with the P region
    float* merge = (float*)smem;   // [3 waves][64 lanes][40 f32] = 30720B
    if(wv != 0){
        float* mb = merge + ((size_t)(wv-1)*64 + l)*40;
        #pragma unroll
        for(int s=0;s<2;s++)
            #pragma unroll
            for(int d=0;d<4;d++)
                #pragma unroll
                for(int r=0;r<4;r++)
                    mb[(s*4+d)*4 + r] = oacc[s][d][r];
        #pragma unroll
        for(int s=0;s<2;s++)
            #pragma unroll
            for(int r=0;r<4;r++)
                mb[32 + s*4 + r] = dacc[s][r];
    }
    __syncthreads();
    if(wv == 0){
        #pragma unroll
        for(int w=0;w<3;w++){
            const float* mb = merge + ((size_t)w*64 + l)*40;
            #pragma unroll
            for(int s=0;s<2;s++)
                #pragma unroll
                for(int d=0;d<4;d++)
                    #pragma unroll
                    for(int r=0;r<4;r++)
                        oacc[s][d][r] += mb[(s*4+d)*4 + r];
            #pragma unroll
            for(int s=0;s<2;s++)
                #pragma unroll
                for(int r=0;r<4;r++)
                    dacc[s][r] += mb[32 + s*4 + r];
        }
        #pragma unroll
        for(int s=0;s<2;s++){
            float inv[4];
            #pragma unroll
            for(int r=0;r<4;r++) inv[r] = 1.0f / dacc[s][r];
            #pragma unroll
            for(int d=0;d<4;d++)
                #pragma unroll
                for(int r=0;r<4;r++)
                    Ab[(size_t)(r0+s*16+g*4+r)*DIM + h*HD + d*16 + l15] =
                        f2bfh(oacc[s][d][r] * inv[r]);
        }
    }
}

// ---------------------------------------------------------------------------
// Kernel 3 (fast path): output projection from bf16 Wout. f32 output.
// ---------------------------------------------------------------------------
__global__ __launch_bounds__(256) void proj_out_b_kernel(
    const unsigned short* __restrict__ Ab,
    const unsigned short* __restrict__ Wob,
    float* __restrict__ out)
{
    const int wv  = threadIdx.x >> 6;
    const int l   = threadIdx.x & 63;
    const int g   = l >> 4;
    const int l15 = l & 15;
    const int r0  = blockIdx.x * 128 + wv * 32;
    const int c0  = blockIdx.y * 64;

    f32x4 acc[2][4];
    #pragma unroll
    for(int s=0;s<2;s++)
        #pragma unroll
        for(int d=0;d<4;d++) acc[s][d] = (f32x4){0.f,0.f,0.f,0.f};

    for(int kt=0; kt<DIM; kt+=32){
        bf16x8 a[2];
        #pragma unroll
        for(int s=0;s<2;s++)
            a[s] = *(const bf16x8*)(Ab + (size_t)(r0+s*16+l15)*DIM + kt + g*8);
        #pragma unroll
        for(int d=0;d<4;d++){
            bf16x8 b = *(const bf16x8*)(Wob + (size_t)(c0+d*16+l15)*DIM + kt + g*8);
            #pragma unroll
            for(int s=0;s<2;s++)
                acc[s][d] = __builtin_amdgcn_mfma_f32_16x16x32_bf16(a[s], b, acc[s][d], 0,0,0);
        }
    }

    #pragma unroll
    for(int s=0;s<2;s++)
        #pragma unroll
        for(int d=0;d<4;d++)
            #pragma unroll
            for(int r=0;r<4;r++)
                out[(size_t)(r0+s*16+g*4+r)*DIM + c0 + d*16 + l15] = acc[s][d][r];
}

// fallback out-proj (f32 Wout with in-loop cvt)
__global__ __launch_bounds__(256) void proj_out_kernel(
    const unsigned short* __restrict__ Ab,
    const float* __restrict__ Wout,
    float* __restrict__ out)
{
    const int wv  = threadIdx.x >> 6;
    const int l   = threadIdx.x & 63;
    const int g   = l >> 4;
    const int l15 = l & 15;
    const int r0  = blockIdx.x * 128 + wv * 32;
    const int c0  = blockIdx.y * 64;

    f32x4 acc[2][4];
    #pragma unroll
    for(int s=0;s<2;s++)
        #pragma unroll
        for(int d=0;d<4;d++) acc[s][d] = (f32x4){0.f,0.f,0.f,0.f};

    for(int kt=0; kt<DIM; kt+=32){
        bf16x8 a[2];
        #pragma unroll
        for(int s=0;s<2;s++)
            a[s] = *(const bf16x8*)(Ab + (size_t)(r0+s*16+l15)*DIM + kt + g*8);
        #pragma unroll
        for(int d=0;d<4;d++){
            bf16x8 b = load8f(Wout + (size_t)(c0+d*16+l15)*DIM + kt + g*8);
            #pragma unroll
            for(int s=0;s<2;s++)
                acc[s][d] = __builtin_amdgcn_mfma_f32_16x16x32_bf16(a[s], b, acc[s][d], 0,0,0);
        }
    }

    #pragma unroll
    for(int s=0;s<2;s++)
        #pragma unroll
        for(int d=0;d<4;d++)
            #pragma unroll
            for(int r=0;r<4;r++)
                out[(size_t)(r0+s*16+g*4+r)*DIM + c0 + d*16 + l15] = acc[s][d][r];
}

// ---------------------------------------------------------------------------
extern "C" void kernel_launch(void* const* d_in, const int* in_sizes, int n_in,
                              void* d_out, int out_size, void* d_ws, size_t ws_size,
                              hipStream_t stream)
{
    const float* x    = (const float*)d_in[0];
    const float* Wq   = (const float*)d_in[1];
    const float* bq   = (const float*)d_in[2];
    const float* Wk   = (const float*)d_in[3];
    const float* bk   = (const float*)d_in[4];
    const float* Wv   = (const float*)d_in[5];
    const float* bv   = (const float*)d_in[6];
    const float* Wout = (const float*)d_in[7];
    float* out = (float*)d_out;

    unsigned short* Qb  = (unsigned short*)d_ws;             // [SEQ][DIM]
    unsigned short* Kh  = Qb  + (size_t)SEQ*DIM;             // [NH][SEQ][HD]
    unsigned short* Vtp = Kh  + (size_t)NH*SEQ*HD;           // [NH][HD][SEQP]
    unsigned short* Ab  = Vtp + (size_t)NH*HD*SEQP;          // [SEQ][DIM]
    unsigned short* xb  = Ab  + (size_t)SEQ*DIM;             // [SEQ][DIM]
    unsigned short* Wqb = xb  + (size_t)SEQ*DIM;             // [DIM][DIM]
    unsigned short* Wkb = Wqb + (size_t)DIM*DIM;
    unsigned short* Wvb = Wkb + (size_t)DIM*DIM;
    unsigned short* Wob = Wvb + (size_t)DIM*DIM;
    const size_t needed = ((size_t)SEQ*DIM*4 + (size_t)NH*HD*SEQP
                           + (size_t)DIM*DIM*4) * 2;

    // quake fast inverse sqrt of HEAD_DIM (replicates numpy f32 ops)
    float xx = 64.0f;
    float x2 = xx * 0.5f;
    int ii; memcpy(&ii, &xx, 4);
    ii = 1597463007 - (ii >> 1);
    float y; memcpy(&y, &ii, 4);
    y = y * (1.5f - x2 * y * y);
    const float scaling = y;
    const float k1f = 12102203.17133801f * scaling;   // GIST_A * scaling (f32)

    if(ws_size >= needed){
        cvt5_kernel<<<dim3(1536), 256, 0, stream>>>(
            x, Wq, Wk, Wv, Wout, xb, Wqb, Wkb, Wvb, Wob);
        proj_qkv_b_kernel<<<dim3(SEQ/128, DIM/64, 3), 256, 0, stream>>>(
            xb, Wqb, bq, Wkb, bk, Wvb, bv, Qb, Kh, Vtp);
        attn_kernel<<<dim3(SEQ/32, NH), 256, 0, stream>>>(Qb, Kh, Vtp, Ab, k1f);
        proj_out_b_kernel<<<dim3(SEQ/128, DIM/64), 256, 0, stream>>>(Ab, Wob, out);
    } else {
        proj_qkv_kernel<<<dim3(SEQ/128, DIM/64, 3), 256, 0, stream>>>(
            x, Wq, bq, Wk, bk, Wv, bv, Qb, Kh, Vtp);
        attn_kernel<<<dim3(SEQ/32, NH), 256, 0, stream>>>(Qb, Kh, Vtp, Ab, k1f);
        proj_out_kernel<<<dim3(SEQ/128, DIM/64), 256, 0, stream>>>(Ab, Wout, out);
    }
}